// Round 1
// baseline (555.036 us; speedup 1.0000x reference)
//
#include <hip/hip_runtime.h>
#include <hip/hip_bf16.h>
#include <math.h>

#define NN 100000
#define NE 1600000
#define NG 512

// ---------------- degree / norm ----------------
__global__ void deg_kernel(const int* __restrict__ dst, int* __restrict__ deg, int e){
    int i = blockIdx.x*blockDim.x + threadIdx.x;
    if(i<e) atomicAdd(&deg[dst[i]], 1);
}
__global__ void dinv_kernel(const int* __restrict__ deg, float* __restrict__ dinv, int n){
    int i = blockIdx.x*blockDim.x + threadIdx.x;
    if(i<n) dinv[i] = rsqrtf((float)(deg[i]+1));   // +1 self-loop
}

// ---------------- exclusive scan of indegree (CSR offsets) ----------------
__global__ void scan_part(const int* __restrict__ deg, int* __restrict__ bsum, int n){
    __shared__ int s[512];
    int i = blockIdx.x*512 + threadIdx.x;
    int v = (i<n)?deg[i]:0;
    s[threadIdx.x]=v; __syncthreads();
    for(int off=256; off>0; off>>=1){
        if(threadIdx.x<off) s[threadIdx.x]+=s[threadIdx.x+off];
        __syncthreads();
    }
    if(threadIdx.x==0) bsum[blockIdx.x]=s[0];
}
__global__ void scan_blocks(const int* __restrict__ bsum, int* __restrict__ boffs, int nb){
    __shared__ int s[256];
    int v = (threadIdx.x<nb)?bsum[threadIdx.x]:0;
    s[threadIdx.x]=v; __syncthreads();
    for(int off=1; off<256; off<<=1){
        int t = (threadIdx.x>=off)? s[threadIdx.x-off]:0;
        __syncthreads();
        s[threadIdx.x]+=t; __syncthreads();
    }
    if(threadIdx.x<nb) boffs[threadIdx.x]=s[threadIdx.x]-v;
}
__global__ void scan_final(const int* __restrict__ deg, const int* __restrict__ boffs,
                           int* __restrict__ row_start, int* __restrict__ ptr, int n){
    __shared__ int s[512];
    int i = blockIdx.x*512 + threadIdx.x;
    int v = (i<n)?deg[i]:0;
    s[threadIdx.x]=v; __syncthreads();
    for(int off=1; off<512; off<<=1){
        int t = (threadIdx.x>=off)? s[threadIdx.x-off]:0;
        __syncthreads();
        s[threadIdx.x]+=t; __syncthreads();
    }
    int excl = boffs[blockIdx.x] + s[threadIdx.x]-v;
    if(i<n){ row_start[i]=excl; ptr[i]=excl; }
}

// ---------------- CSR fill: csr[pos] = {src, norm} ----------------
__global__ void fill_kernel(const int* __restrict__ src, const int* __restrict__ dst,
                            const float* __restrict__ dinv, int* __restrict__ ptr,
                            int2* __restrict__ csr, int e){
    int i = blockIdx.x*blockDim.x + threadIdx.x;
    if(i>=e) return;
    int s = src[i], d = dst[i];
    float w = dinv[s]*dinv[d];
    int pos = atomicAdd(&ptr[d], 1);   // after kernel: ptr[i] == row_end[i]
    csr[pos] = make_int2(s, __float_as_int(w));
}

// ---------------- dense GEMM: Y[n,NCOL] = X[n,K] @ W[K,NCOL] (+bias,relu) ----------------
// 8 rows x 4 cols per thread; W staged in LDS (float4, conflict-free); X straight from global.
template<int K, int NCOL, bool BIAS, bool RELU>
__global__ __launch_bounds__(256) void gemm_kernel(const float* __restrict__ X, const float* __restrict__ W,
                                                   const float* __restrict__ bias, float* __restrict__ Y, int n){
    constexpr int CG = NCOL/4;      // col groups of 4
    constexpr int RT = 256/CG;      // row-threads
    constexpr int RPT = 8;          // rows per thread
    constexpr int ROWS = RT*RPT;    // rows per block
    __shared__ float sW[K*NCOL];
    for(int i=threadIdx.x; i<K*NCOL/4; i+=256)
        ((float4*)sW)[i] = ((const float4*)W)[i];
    __syncthreads();
    int cg = threadIdx.x % CG;
    int rt = threadIdx.x / CG;
    int base = blockIdx.x*ROWS + rt*RPT;
    float acc[RPT][4];
    #pragma unroll
    for(int j=0;j<RPT;j++){ acc[j][0]=0.f; acc[j][1]=0.f; acc[j][2]=0.f; acc[j][3]=0.f; }
    const float* xp[RPT];
    #pragma unroll
    for(int j=0;j<RPT;j++){
        int r = base+j; if(r>n-1) r=n-1;          // clamp (store is guarded)
        xp[j] = X + (size_t)r*K;
    }
    for(int k4=0;k4<K/4;k4++){
        float4 w0 = *(const float4*)&sW[(k4*4+0)*NCOL + cg*4];
        float4 w1 = *(const float4*)&sW[(k4*4+1)*NCOL + cg*4];
        float4 w2 = *(const float4*)&sW[(k4*4+2)*NCOL + cg*4];
        float4 w3 = *(const float4*)&sW[(k4*4+3)*NCOL + cg*4];
        #pragma unroll
        for(int j=0;j<RPT;j++){
            float4 xv = ((const float4*)xp[j])[k4];
            acc[j][0] += xv.x*w0.x + xv.y*w1.x + xv.z*w2.x + xv.w*w3.x;
            acc[j][1] += xv.x*w0.y + xv.y*w1.y + xv.z*w2.y + xv.w*w3.y;
            acc[j][2] += xv.x*w0.z + xv.y*w1.z + xv.z*w2.z + xv.w*w3.z;
            acc[j][3] += xv.x*w0.w + xv.y*w1.w + xv.z*w2.w + xv.w*w3.w;
        }
    }
    float4 bv = make_float4(0.f,0.f,0.f,0.f);
    if constexpr(BIAS) bv = *(const float4*)&bias[cg*4];
    #pragma unroll
    for(int j=0;j<RPT;j++){
        int r = base+j;
        if(r<n){
            float4 o;
            o.x = acc[j][0]+bv.x; o.y = acc[j][1]+bv.y;
            o.z = acc[j][2]+bv.z; o.w = acc[j][3]+bv.w;
            if constexpr(RELU){
                o.x=fmaxf(o.x,0.f); o.y=fmaxf(o.y,0.f);
                o.z=fmaxf(o.z,0.f); o.w=fmaxf(o.w,0.f);
            }
            *(float4*)&Y[(size_t)r*NCOL + cg*4] = o;
        }
    }
}

// ---------------- pull-based propagate: out[i] = dinv_i^2*x[i] + sum_e w_e*x[src_e] ----------------
template<int F, bool BIAS, bool RELU>
__global__ __launch_bounds__(256) void prop_kernel(const float* __restrict__ xin, float* __restrict__ xout,
                                                   const int2* __restrict__ csr, const int* __restrict__ row_start,
                                                   const int* __restrict__ row_end, const float* __restrict__ dinv,
                                                   const float* __restrict__ bias, int n){
    int node = (blockIdx.x*256 + threadIdx.x)/F;
    int f    = threadIdx.x % F;
    if(node>=n) return;
    float di = dinv[node];
    float acc = di*di*xin[(size_t)node*F + f];
    int e  = row_start[node];
    int ee = row_end[node];
    for(; e+1<ee; e+=2){
        int2 m0 = csr[e];
        int2 m1 = csr[e+1];
        acc += __int_as_float(m0.y)*xin[(size_t)m0.x*F + f];
        acc += __int_as_float(m1.y)*xin[(size_t)m1.x*F + f];
    }
    if(e<ee){
        int2 m = csr[e];
        acc += __int_as_float(m.y)*xin[(size_t)m.x*F + f];
    }
    if constexpr(BIAS) acc += bias[f];
    if constexpr(RELU) acc = fmaxf(acc,0.f);
    xout[(size_t)node*F + f] = acc;
}

// ---------------- graph pooling (batch is sorted -> binary search boundaries) ----------------
__global__ void pool_kernel(const float* __restrict__ p3, const int* __restrict__ batch,
                            float* __restrict__ pool, int* __restrict__ cnt, int n){
    int g = blockIdx.x;
    int lo=0, hi=n;
    while(lo<hi){ int mid=(lo+hi)>>1; if(batch[mid]<g) lo=mid+1; else hi=mid; }
    int start=lo;
    lo=start; hi=n;
    while(lo<hi){ int mid=(lo+hi)>>1; if(batch[mid]<g+1) lo=mid+1; else hi=mid; }
    int end=lo;
    float a0=0.f,a1=0.f,a2=0.f,a3=0.f;
    int i=start;
    for(; i+3<end; i+=4){
        a0 += p3[(size_t)i    *64 + threadIdx.x];
        a1 += p3[(size_t)(i+1)*64 + threadIdx.x];
        a2 += p3[(size_t)(i+2)*64 + threadIdx.x];
        a3 += p3[(size_t)(i+3)*64 + threadIdx.x];
    }
    for(; i<end; ++i) a0 += p3[(size_t)i*64 + threadIdx.x];
    pool[g*64+threadIdx.x] = (a0+a1)+(a2+a3);
    if(threadIdx.x==0) cnt[g] = end-start;
}

// ---------------- head: g3 = pool@W3 + cnt*b3; h=relu(g3@Wl1+bl1); logits=h@Wl2+bl2; log_softmax ----------------
__global__ __launch_bounds__(128) void head_kernel(const float* __restrict__ pool, const int* __restrict__ cnt,
                                                   const float* __restrict__ W3, const float* __restrict__ b3,
                                                   const float* __restrict__ Wl1, const float* __restrict__ bl1,
                                                   const float* __restrict__ Wl2, const float* __restrict__ bl2,
                                                   float* __restrict__ out){
    __shared__ float sp[64];
    __shared__ float sg3[128];
    __shared__ float sh[64];
    __shared__ float sl[10];
    int g = blockIdx.x, t = threadIdx.x;
    if(t<64) sp[t] = pool[g*64+t];
    __syncthreads();
    float cf = (float)cnt[g];
    float a = cf*b3[t];
    #pragma unroll 8
    for(int k=0;k<64;k++) a += sp[k]*W3[k*128+t];
    sg3[t]=a; __syncthreads();
    if(t<64){
        float h = bl1[t];
        #pragma unroll 8
        for(int k=0;k<128;k++) h += sg3[k]*Wl1[k*64+t];
        sh[t] = fmaxf(h,0.f);
    }
    __syncthreads();
    if(t<10){
        float l = bl2[t];
        for(int k=0;k<64;k++) l += sh[k]*Wl2[k*10+t];
        sl[t]=l;
    }
    __syncthreads();
    if(t<10){
        float m=sl[0];
        for(int k=1;k<10;k++) m=fmaxf(m,sl[k]);
        float s=0.f;
        for(int k=0;k<10;k++) s+=expf(sl[k]-m);
        out[g*10+t] = sl[t]-m-logf(s);
    }
}

extern "C" void kernel_launch(void* const* d_in, const int* in_sizes, int n_in,
                              void* d_out, int out_size, void* d_ws, size_t ws_size,
                              hipStream_t stream){
    const float* x   = (const float*)d_in[0];
    const int*   ei  = (const int*)d_in[1];
    const int* batch = (const int*)d_in[2];
    const float* W1  = (const float*)d_in[3];
    const float* b1  = (const float*)d_in[4];
    const float* W2  = (const float*)d_in[5];
    const float* b2  = (const float*)d_in[6];
    const float* W3  = (const float*)d_in[7];
    const float* b3  = (const float*)d_in[8];
    const float* Wl1 = (const float*)d_in[9];
    const float* bl1 = (const float*)d_in[10];
    const float* Wl2 = (const float*)d_in[11];
    const float* bl2 = (const float*)d_in[12];
    const int n = NN, E = NE;
    const int* src = ei;        // edge_index[0]
    const int* dst = ei + E;    // edge_index[1]

    char* ws = (char*)d_ws;
    size_t off = 0;
    auto alloc = [&](size_t bytes)->char*{
        char* p = ws + off;
        off = (off + bytes + 255) & ~(size_t)255;
        return p;
    };
    int*   deg       = (int*)  alloc((size_t)n*4);
    int*   row_start = (int*)  alloc((size_t)n*4);
    int*   ptr       = (int*)  alloc((size_t)n*4);
    float* dinv      = (float*)alloc((size_t)n*4);
    int*   bsum      = (int*)  alloc(256*4);
    int*   boffs     = (int*)  alloc(256*4);
    int2*  csr       = (int2*) alloc((size_t)E*8);
    float* bufA      = (float*)alloc((size_t)n*64*4);  // xw1 (32c) then p3 (64c)
    float* bufB      = (float*)alloc((size_t)n*64*4);  // h1 (32c) then h2 (64c)
    float* bufC      = (float*)alloc((size_t)n*32*4);  // p2 (32c)
    float* pool      = (float*)alloc((size_t)NG*64*4);
    int*   cnt       = (int*)  alloc((size_t)NG*4);

    hipMemsetAsync(deg, 0, (size_t)n*4, stream);
    deg_kernel<<<(E+255)/256,256,0,stream>>>(dst, deg, E);
    dinv_kernel<<<(n+255)/256,256,0,stream>>>(deg, dinv, n);
    const int NB = (n+511)/512;
    scan_part  <<<NB,512,0,stream>>>(deg, bsum, n);
    scan_blocks<<<1,256,0,stream>>>(bsum, boffs, NB);
    scan_final <<<NB,512,0,stream>>>(deg, boffs, row_start, ptr, n);
    fill_kernel<<<(E+255)/256,256,0,stream>>>(src, dst, dinv, ptr, csr, E);

    // layer 1: xw1 = x@W1 ; h1 = relu(prop(xw1) + b1)
    gemm_kernel<128,32,false,false><<<(n+255)/256,256,0,stream>>>(x, W1, nullptr, bufA, n);
    prop_kernel<32,true,true><<<(n*32+255)/256,256,0,stream>>>(bufA, bufB, csr, row_start, ptr, dinv, b1, n);
    // layer 2 (prop-first): p2 = prop(h1) ; h2 = relu(p2@W2 + b2)
    prop_kernel<32,false,false><<<(n*32+255)/256,256,0,stream>>>(bufB, bufC, csr, row_start, ptr, dinv, nullptr, n);
    gemm_kernel<32,64,true,true><<<(n+127)/128,256,0,stream>>>(bufC, W2, b2, bufB, n);
    // layer 3 (prop-first, GEMM folded past pooling): p3 = prop(h2)
    prop_kernel<64,false,false><<<(n*64+255)/256,256,0,stream>>>(bufB, bufA, csr, row_start, ptr, dinv, nullptr, n);
    // pool pre-GEMM features, then tiny head does pool@W3 + cnt*b3, MLP, log_softmax
    pool_kernel<<<NG,64,0,stream>>>(bufA, batch, pool, cnt, n);
    head_kernel<<<NG,128,0,stream>>>(pool, cnt, W3, b3, Wl1, bl1, Wl2, bl2, (float*)d_out);
}

// Round 2
// 548.575 us; speedup vs baseline: 1.0118x; 1.0118x over previous
//
#include <hip/hip_runtime.h>
#include <hip/hip_bf16.h>
#include <math.h>

#define NN 100000
#define NE 1600000
#define NG 512

// ---------------- degree / norm ----------------
__global__ void deg_kernel(const int* __restrict__ dst, int* __restrict__ deg, int e){
    int i = blockIdx.x*blockDim.x + threadIdx.x;
    if(i<e) atomicAdd(&deg[dst[i]], 1);
}
__global__ void dinv_kernel(const int* __restrict__ deg, float* __restrict__ dinv, int n){
    int i = blockIdx.x*blockDim.x + threadIdx.x;
    if(i<n) dinv[i] = rsqrtf((float)(deg[i]+1));   // +1 self-loop
}

// ---------------- exclusive scan of indegree (CSR offsets) ----------------
__global__ void scan_part(const int* __restrict__ deg, int* __restrict__ bsum, int n){
    __shared__ int s[512];
    int i = blockIdx.x*512 + threadIdx.x;
    int v = (i<n)?deg[i]:0;
    s[threadIdx.x]=v; __syncthreads();
    for(int off=256; off>0; off>>=1){
        if(threadIdx.x<off) s[threadIdx.x]+=s[threadIdx.x+off];
        __syncthreads();
    }
    if(threadIdx.x==0) bsum[blockIdx.x]=s[0];
}
__global__ void scan_blocks(const int* __restrict__ bsum, int* __restrict__ boffs, int nb){
    __shared__ int s[256];
    int v = (threadIdx.x<nb)?bsum[threadIdx.x]:0;
    s[threadIdx.x]=v; __syncthreads();
    for(int off=1; off<256; off<<=1){
        int t = (threadIdx.x>=off)? s[threadIdx.x-off]:0;
        __syncthreads();
        s[threadIdx.x]+=t; __syncthreads();
    }
    if(threadIdx.x<nb) boffs[threadIdx.x]=s[threadIdx.x]-v;
}
__global__ void scan_final(const int* __restrict__ deg, const int* __restrict__ boffs,
                           int* __restrict__ row_start, int* __restrict__ ptr, int n){
    __shared__ int s[512];
    int i = blockIdx.x*512 + threadIdx.x;
    int v = (i<n)?deg[i]:0;
    s[threadIdx.x]=v; __syncthreads();
    for(int off=1; off<512; off<<=1){
        int t = (threadIdx.x>=off)? s[threadIdx.x-off]:0;
        __syncthreads();
        s[threadIdx.x]+=t; __syncthreads();
    }
    int excl = boffs[blockIdx.x] + s[threadIdx.x]-v;
    if(i<n){ row_start[i]=excl; ptr[i]=excl; }
}

// ---------------- CSR fill: csr[pos] = src  (4B entries; weights are factored out) ----------------
__global__ void fill_kernel(const int* __restrict__ src, const int* __restrict__ dst,
                            int* __restrict__ ptr, int* __restrict__ csr, int e){
    int i = blockIdx.x*blockDim.x + threadIdx.x;
    if(i>=e) return;
    int d = dst[i];
    int pos = atomicAdd(&ptr[d], 1);   // after kernel: ptr[i] == row_end[i]
    csr[pos] = src[i];
}

// ---------------- dense GEMM: Y[n,NCOL] = scale_r * (relu(X[n,K] @ W[K,NCOL] + b)) ----------------
// 8 rows x 4 cols per thread; W staged in LDS; optional dinv[row] output scaling.
template<int K, int NCOL, bool BIAS, bool RELU, bool SCALE>
__global__ __launch_bounds__(256) void gemm_kernel(const float* __restrict__ X, const float* __restrict__ W,
                                                   const float* __restrict__ bias, const float* __restrict__ dinv,
                                                   float* __restrict__ Y, int n){
    constexpr int CG = NCOL/4;      // col groups of 4
    constexpr int RT = 256/CG;      // row-threads
    constexpr int RPT = 8;          // rows per thread
    constexpr int ROWS = RT*RPT;    // rows per block
    __shared__ float sW[K*NCOL];
    for(int i=threadIdx.x; i<K*NCOL/4; i+=256)
        ((float4*)sW)[i] = ((const float4*)W)[i];
    __syncthreads();
    int cg = threadIdx.x % CG;
    int rt = threadIdx.x / CG;
    int base = blockIdx.x*ROWS + rt*RPT;
    float acc[RPT][4];
    #pragma unroll
    for(int j=0;j<RPT;j++){ acc[j][0]=0.f; acc[j][1]=0.f; acc[j][2]=0.f; acc[j][3]=0.f; }
    const float* xp[RPT];
    #pragma unroll
    for(int j=0;j<RPT;j++){
        int r = base+j; if(r>n-1) r=n-1;          // clamp (store is guarded)
        xp[j] = X + (size_t)r*K;
    }
    for(int k4=0;k4<K/4;k4++){
        float4 w0 = *(const float4*)&sW[(k4*4+0)*NCOL + cg*4];
        float4 w1 = *(const float4*)&sW[(k4*4+1)*NCOL + cg*4];
        float4 w2 = *(const float4*)&sW[(k4*4+2)*NCOL + cg*4];
        float4 w3 = *(const float4*)&sW[(k4*4+3)*NCOL + cg*4];
        #pragma unroll
        for(int j=0;j<RPT;j++){
            float4 xv = ((const float4*)xp[j])[k4];
            acc[j][0] += xv.x*w0.x + xv.y*w1.x + xv.z*w2.x + xv.w*w3.x;
            acc[j][1] += xv.x*w0.y + xv.y*w1.y + xv.z*w2.y + xv.w*w3.y;
            acc[j][2] += xv.x*w0.z + xv.y*w1.z + xv.z*w2.z + xv.w*w3.z;
            acc[j][3] += xv.x*w0.w + xv.y*w1.w + xv.z*w2.w + xv.w*w3.w;
        }
    }
    float4 bv = make_float4(0.f,0.f,0.f,0.f);
    if constexpr(BIAS) bv = *(const float4*)&bias[cg*4];
    #pragma unroll
    for(int j=0;j<RPT;j++){
        int r = base+j;
        if(r<n){
            float4 o;
            o.x = acc[j][0]+bv.x; o.y = acc[j][1]+bv.y;
            o.z = acc[j][2]+bv.z; o.w = acc[j][3]+bv.w;
            if constexpr(RELU){
                o.x=fmaxf(o.x,0.f); o.y=fmaxf(o.y,0.f);
                o.z=fmaxf(o.z,0.f); o.w=fmaxf(o.w,0.f);
            }
            if constexpr(SCALE){
                float s = dinv[r];
                o.x*=s; o.y*=s; o.z*=s; o.w*=s;
            }
            *(float4*)&Y[(size_t)r*NCOL + cg*4] = o;
        }
    }
}

// ---------------- pull-based propagate on pre-scaled features ----------------
// in: y[j] (already multiplied by dinv[j] at the producer)
// out[i] = POST( di * (y[i] + sum_{e:dst=i} y[src_e]) )   with POST = (+bias, relu, *di) options
template<int F, bool BIAS, bool RELU, bool POSTSCALE>
__global__ __launch_bounds__(256) void prop_kernel(const float* __restrict__ xin, float* __restrict__ xout,
                                                   const int* __restrict__ csr, const int* __restrict__ row_start,
                                                   const int* __restrict__ row_end, const float* __restrict__ dinv,
                                                   const float* __restrict__ bias, int n){
    int node = (blockIdx.x*256 + threadIdx.x)/F;
    int f    = threadIdx.x & (F-1);
    if(node>=n) return;
    float di = dinv[node];
    const float* __restrict__ xf = xin + f;
    float a0 = xf[(size_t)node*F];   // self-loop term (pre-scaled)
    float a1 = 0.f, a2 = 0.f, a3 = 0.f;
    int e  = row_start[node];
    int ee = row_end[node];
    for(; e+3<ee; e+=4){
        int s0 = csr[e];
        int s1 = csr[e+1];
        int s2 = csr[e+2];
        int s3 = csr[e+3];
        a0 += xf[(size_t)s0*F];
        a1 += xf[(size_t)s1*F];
        a2 += xf[(size_t)s2*F];
        a3 += xf[(size_t)s3*F];
    }
    for(; e<ee; ++e) a0 += xf[(size_t)csr[e]*F];
    float r = di*((a0+a1)+(a2+a3));
    if constexpr(BIAS) r += bias[f];
    if constexpr(RELU) r = fmaxf(r,0.f);
    if constexpr(POSTSCALE) r *= di;
    xout[(size_t)node*F + f] = r;
}

// ---------------- graph pooling (batch is sorted -> binary search boundaries) ----------------
__global__ __launch_bounds__(256) void pool_kernel(const float* __restrict__ p3, const int* __restrict__ batch,
                                                   float* __restrict__ pool, int* __restrict__ cnt, int n){
    __shared__ float red[256];
    int g = blockIdx.x;
    int lo=0, hi=n;
    while(lo<hi){ int mid=(lo+hi)>>1; if(batch[mid]<g) lo=mid+1; else hi=mid; }
    int start=lo;
    lo=start; hi=n;
    while(lo<hi){ int mid=(lo+hi)>>1; if(batch[mid]<g+1) lo=mid+1; else hi=mid; }
    int end=lo;
    int f  = threadIdx.x & 63;
    int r4 = threadIdx.x >> 6;    // 0..3
    float a = 0.f;
    for(int i=start+r4; i<end; i+=4) a += p3[(size_t)i*64 + f];
    red[threadIdx.x]=a; __syncthreads();
    if(threadIdx.x<128) red[threadIdx.x]+=red[threadIdx.x+128];
    __syncthreads();
    if(threadIdx.x<64) pool[g*64+threadIdx.x] = red[threadIdx.x]+red[threadIdx.x+64];
    if(threadIdx.x==0) cnt[g] = end-start;
}

// ---------------- head: g3 = pool@W3 + cnt*b3; h=relu(g3@Wl1+bl1); logits=h@Wl2+bl2; log_softmax ----------------
__global__ __launch_bounds__(128) void head_kernel(const float* __restrict__ pool, const int* __restrict__ cnt,
                                                   const float* __restrict__ W3, const float* __restrict__ b3,
                                                   const float* __restrict__ Wl1, const float* __restrict__ bl1,
                                                   const float* __restrict__ Wl2, const float* __restrict__ bl2,
                                                   float* __restrict__ out){
    __shared__ float sp[64];
    __shared__ float sg3[128];
    __shared__ float sh[64];
    __shared__ float sl[10];
    int g = blockIdx.x, t = threadIdx.x;
    if(t<64) sp[t] = pool[g*64+t];
    __syncthreads();
    float cf = (float)cnt[g];
    float a = cf*b3[t];
    #pragma unroll 8
    for(int k=0;k<64;k++) a += sp[k]*W3[k*128+t];
    sg3[t]=a; __syncthreads();
    if(t<64){
        float h = bl1[t];
        #pragma unroll 8
        for(int k=0;k<128;k++) h += sg3[k]*Wl1[k*64+t];
        sh[t] = fmaxf(h,0.f);
    }
    __syncthreads();
    if(t<10){
        float l = bl2[t];
        for(int k=0;k<64;k++) l += sh[k]*Wl2[k*10+t];
        sl[t]=l;
    }
    __syncthreads();
    if(t<10){
        float m=sl[0];
        for(int k=1;k<10;k++) m=fmaxf(m,sl[k]);
        float s=0.f;
        for(int k=0;k<10;k++) s+=expf(sl[k]-m);
        out[g*10+t] = sl[t]-m-logf(s);
    }
}

extern "C" void kernel_launch(void* const* d_in, const int* in_sizes, int n_in,
                              void* d_out, int out_size, void* d_ws, size_t ws_size,
                              hipStream_t stream){
    const float* x   = (const float*)d_in[0];
    const int*   ei  = (const int*)d_in[1];
    const int* batch = (const int*)d_in[2];
    const float* W1  = (const float*)d_in[3];
    const float* b1  = (const float*)d_in[4];
    const float* W2  = (const float*)d_in[5];
    const float* b2  = (const float*)d_in[6];
    const float* W3  = (const float*)d_in[7];
    const float* b3  = (const float*)d_in[8];
    const float* Wl1 = (const float*)d_in[9];
    const float* bl1 = (const float*)d_in[10];
    const float* Wl2 = (const float*)d_in[11];
    const float* bl2 = (const float*)d_in[12];
    const int n = NN, E = NE;
    const int* src = ei;        // edge_index[0]
    const int* dst = ei + E;    // edge_index[1]

    char* ws = (char*)d_ws;
    size_t off = 0;
    auto alloc = [&](size_t bytes)->char*{
        char* p = ws + off;
        off = (off + bytes + 255) & ~(size_t)255;
        return p;
    };
    int*   deg       = (int*)  alloc((size_t)n*4);
    int*   row_start = (int*)  alloc((size_t)n*4);
    int*   ptr       = (int*)  alloc((size_t)n*4);
    float* dinv      = (float*)alloc((size_t)n*4);
    int*   bsum      = (int*)  alloc(256*4);
    int*   boffs     = (int*)  alloc(256*4);
    int*   csr       = (int*)  alloc((size_t)E*4);
    float* bufA      = (float*)alloc((size_t)n*64*4);  // y1 (32c) then p3 (64c)
    float* bufB      = (float*)alloc((size_t)n*64*4);  // h1y (32c) then h2y (64c)
    float* bufC      = (float*)alloc((size_t)n*32*4);  // p2 (32c)
    float* pool      = (float*)alloc((size_t)NG*64*4);
    int*   cnt       = (int*)  alloc((size_t)NG*4);

    hipMemsetAsync(deg, 0, (size_t)n*4, stream);
    deg_kernel<<<(E+255)/256,256,0,stream>>>(dst, deg, E);
    dinv_kernel<<<(n+255)/256,256,0,stream>>>(deg, dinv, n);
    const int NB = (n+511)/512;
    scan_part  <<<NB,512,0,stream>>>(deg, bsum, n);
    scan_blocks<<<1,256,0,stream>>>(bsum, boffs, NB);
    scan_final <<<NB,512,0,stream>>>(deg, boffs, row_start, ptr, n);
    fill_kernel<<<(E+255)/256,256,0,stream>>>(src, dst, ptr, csr, E);

    // layer 1: y1 = dinv .* (x@W1);  h1y = dinv .* relu(dinv*(y1self+sum) + b1)
    gemm_kernel<128,32,false,false,true><<<(n+255)/256,256,0,stream>>>(x, W1, nullptr, dinv, bufA, n);
    prop_kernel<32,true,true,true><<<(n*32+255)/256,256,0,stream>>>(bufA, bufB, csr, row_start, ptr, dinv, b1, n);
    // layer 2 (prop-first): p2 = dinv .* (h1y self+sum);  h2y = dinv .* relu(p2@W2 + b2)
    prop_kernel<32,false,false,false><<<(n*32+255)/256,256,0,stream>>>(bufB, bufC, csr, row_start, ptr, dinv, nullptr, n);
    gemm_kernel<32,64,true,true,true><<<(n+127)/128,256,0,stream>>>(bufC, W2, b2, dinv, bufB, n);
    // layer 3 (prop-first, GEMM folded past pooling): p3 = dinv .* (h2y self+sum)
    prop_kernel<64,false,false,false><<<(n*64+255)/256,256,0,stream>>>(bufB, bufA, csr, row_start, ptr, dinv, nullptr, n);
    // pool pre-GEMM features, then tiny head does pool@W3 + cnt*b3, MLP, log_softmax
    pool_kernel<<<NG,256,0,stream>>>(bufA, batch, pool, cnt, n);
    head_kernel<<<NG,128,0,stream>>>(pool, cnt, W3, b3, Wl1, bl1, Wl2, bl2, (float*)d_out);
}